// Round 5
// baseline (12404.359 us; speedup 1.0000x reference)
//
#include <hip/hip_runtime.h>
#include <math.h>

// DrugGraphConv: 5000 graphs x 100 nodes x 400 edges, 5 TAGConv(K=2) layers
// DIMS = [74,70,65,60,55,37], gated softmax pooling per graph.
//
// R4 (3.49 ms): lane=node + SGPR weights killed spills, but per-k
// ds_read_b32 + s_load on the shared lgkmcnt counter serialized the GEMM
// (one ~120cyc drain per k), and propagate chained 2 LDS latencies per edge.
//
// R5: STRIDE=76; gblock reads h via fully-unrolled ds_read_b128 chunks
// (all reads issued ahead of FMA batches); h cols zero-padded to x4 so the
// k-tail uses a wave-uniform clamped W row (h_pad=0 contributes nothing).
// propagate: csr_val[e]=nrm[src] precomputed, 4-edge batches of independent
// LDS reads, float4 accumulator.

constexpr int NODES  = 100;
constexpr int EDGES  = 400;
constexpr int STRIDE = 76;     // x4 floats; 12n mod 32 start banks -> all 32 banks, 2-way = free
constexpr int NTHR   = 512;

struct __align__(16) Smem {
    float bufA[NODES * STRIDE];   // 30,400 B
    float bufB[NODES * STRIDE];   // 30,400 B
    int   csr_src[EDGES];         //  1,600 B
    float csr_val[EDGES];         //  1,600 B  (nrm[src] per CSR slot)
    int   row_start[NODES + 1];   //    404 B
    int   cnt[NODES];             //    400 B
    float nrm[NODES];             //    400 B
    float gate[NODES];            //    400 B   => 65,604 B (2 blocks/CU)
};

// out[n][:] = nrm[n] * sum_{e: dst==n} csr_val[e] * in[src_e][:]
template<int D_IN>
__device__ __forceinline__ void propagate(const float* __restrict__ in,
                                          float* __restrict__ outb,
                                          const int* __restrict__ csr_src,
                                          const float* __restrict__ csr_val,
                                          const int* __restrict__ row_start,
                                          const float* __restrict__ nrm,
                                          int tid)
{
    constexpr int CH = (D_IN + 3) / 4;            // float4 chunks (incl. pad)
    const float4* __restrict__ in4 = (const float4*)in;
    float4* __restrict__ out4 = (float4*)outb;
    constexpr int R4 = STRIDE / 4;                // row stride in float4 (19)

    for (int t = tid; t < NODES * CH; t += NTHR) {
        int n = t / CH;                           // compile-time divisor
        int c = t - n * CH;
        int beg = row_start[n], end = row_start[n + 1];
        float ax = 0.f, ay = 0.f, az = 0.f, aw = 0.f;
        int e = beg;
        for (; e + 3 < end; e += 4) {
            int   s0 = csr_src[e],     s1 = csr_src[e + 1];
            int   s2 = csr_src[e + 2], s3 = csr_src[e + 3];
            float c0 = csr_val[e],     c1 = csr_val[e + 1];
            float c2 = csr_val[e + 2], c3 = csr_val[e + 3];
            float4 v0 = in4[s0 * R4 + c];
            float4 v1 = in4[s1 * R4 + c];
            float4 v2 = in4[s2 * R4 + c];
            float4 v3 = in4[s3 * R4 + c];
            ax = fmaf(c0, v0.x, ax); ay = fmaf(c0, v0.y, ay);
            az = fmaf(c0, v0.z, az); aw = fmaf(c0, v0.w, aw);
            ax = fmaf(c1, v1.x, ax); ay = fmaf(c1, v1.y, ay);
            az = fmaf(c1, v1.z, az); aw = fmaf(c1, v1.w, aw);
            ax = fmaf(c2, v2.x, ax); ay = fmaf(c2, v2.y, ay);
            az = fmaf(c2, v2.z, az); aw = fmaf(c2, v2.w, aw);
            ax = fmaf(c3, v3.x, ax); ay = fmaf(c3, v3.y, ay);
            az = fmaf(c3, v3.z, az); aw = fmaf(c3, v3.w, aw);
        }
        for (; e < end; ++e) {
            int s = csr_src[e];
            float sc = csr_val[e];
            float4 v = in4[s * R4 + c];
            ax = fmaf(sc, v.x, ax); ay = fmaf(sc, v.y, ay);
            az = fmaf(sc, v.z, az); aw = fmaf(sc, v.w, aw);
        }
        float sn = nrm[n];
        float4 o = { ax * sn, ay * sn, az * sn, aw * sn };
        out4[n * R4 + c] = o;
    }
}

template<int D_IN, int D_OUT>
__device__ __forceinline__ void tag_layer(Smem& sm,
                                          const float* __restrict__ W,
                                          const float* __restrict__ Bv,
                                          int tid)
{
    constexpr int CW = (D_OUT + 3) / 4;         // cols per col-group (<=18)
    constexpr int CH = (D_IN + 3) / 4;          // k chunks (h is zero-padded)

    const int wave    = __builtin_amdgcn_readfirstlane(tid >> 6); // 0..7 uniform
    const int lane    = tid & 63;
    const int cgrp    = wave >> 1;              // 0..3  (uniform)
    const int nhalf   = wave & 1;               // 0..1  (uniform)
    const int node    = nhalf * 64 + lane;
    const int nclamp  = node > NODES - 1 ? NODES - 1 : node;
    const int colbase = cgrp * CW;              // uniform

    float acc[CW];
#pragma unroll
    for (int j = 0; j < CW; ++j) acc[j] = 0.f;

    auto gblock = [&](const float* __restrict__ buf, int b) {
        const float* __restrict__ Wb = W + b * D_IN * D_OUT;
        const float4* __restrict__ hrow4 =
            (const float4*)(buf + nclamp * STRIDE);
#pragma unroll
        for (int cc = 0; cc < CH; ++cc) {
            const float4 h4 = hrow4[cc];        // ds_read_b128, 2-way banks
            const float hv[4] = { h4.x, h4.y, h4.z, h4.w };
#pragma unroll
            for (int i = 0; i < 4; ++i) {
                int k = 4 * cc + i;
                int kc = k < D_IN ? k : D_IN - 1;   // uniform clamp; h pad = 0
                const float* __restrict__ wrow = Wb + kc * D_OUT;
#pragma unroll
                for (int j = 0; j < CW; ++j) {
                    int c = colbase + j;            // uniform
                    if (c > D_OUT - 1) c = D_OUT - 1;
                    acc[j] = fmaf(hv[i], wrow[c], acc[j]);  // W via SGPR
                }
            }
        }
    };

    // feats block 0: h (bufA); then hop1 bufA->bufB (bufB dead, no race)
    gblock(sm.bufA, 0);
    propagate<D_IN>(sm.bufA, sm.bufB, sm.csr_src, sm.csr_val,
                    sm.row_start, sm.nrm, tid);
    __syncthreads();
    // feats block 1: hop1 (bufB); then hop2 bufB->bufA (bufA reads all done)
    gblock(sm.bufB, 1);
    propagate<D_IN>(sm.bufB, sm.bufA, sm.csr_src, sm.csr_val,
                    sm.row_start, sm.nrm, tid);
    __syncthreads();
    // feats block 2: hop2 (bufA)
    gblock(sm.bufA, 2);
    __syncthreads();    // all reads of bufA complete before h' overwrite

    if (node < NODES) {
#pragma unroll
        for (int j = 0; j < CW; ++j) {
            int c = colbase + j;
            if (c < D_OUT)
                sm.bufA[node * STRIDE + c] = fmaxf(acc[j] + Bv[c], 0.f);
        }
    }
    // zero-pad cols [D_OUT, 4*ceil(D_OUT/4)) for next layer's b128 tail
    constexpr int PAD = (4 - (D_OUT & 3)) & 3;
    if constexpr (PAD > 0) {
        for (int t = tid; t < NODES * PAD; t += NTHR) {
            int n = t / PAD;
            int p = t - n * PAD;
            sm.bufA[n * STRIDE + D_OUT + p] = 0.f;
        }
    }
    __syncthreads();
}

__global__ __launch_bounds__(NTHR, 2)
void drug_graph_conv_kernel(
    const float* __restrict__ x,
    const int*   __restrict__ src,
    const int*   __restrict__ dst,
    const float* __restrict__ W0, const float* __restrict__ b0,
    const float* __restrict__ W1, const float* __restrict__ b1,
    const float* __restrict__ W2, const float* __restrict__ b2,
    const float* __restrict__ W3, const float* __restrict__ b3,
    const float* __restrict__ W4, const float* __restrict__ b4,
    const float* __restrict__ gate_w, const float* __restrict__ gate_b,
    float* __restrict__ out)
{
    __shared__ Smem sm;
    const int g     = blockIdx.x;
    const int tid   = threadIdx.x;
    const int nbase = g * NODES;

    // ---- stage x (100 x 74) into bufA at stride 76; zero pad cols 74,75 ----
    for (int t = tid; t < NODES * 74; t += NTHR) {
        int n = t / 74;
        int d = t - n * 74;
        sm.bufA[n * STRIDE + d] = x[nbase * 74 + t];
    }
    for (int t = tid; t < NODES * 2; t += NTHR) {
        int n = t >> 1;
        sm.bufA[n * STRIDE + 74 + (t & 1)] = 0.f;
    }

    // ---- degree count ----
    if (tid < NODES) sm.cnt[tid] = 0;
    __syncthreads();
    int es = 0, ed = 0;
    const bool ethr = tid < EDGES;
    if (ethr) {
        es = src[g * EDGES + tid] - nbase;
        ed = dst[g * EDGES + tid] - nbase;
        atomicAdd(&sm.cnt[ed], 1);
    }
    __syncthreads();

    // ---- norm + CSR row offsets (wave-0 shuffle scan over 100 degrees) ----
    if (tid < NODES) sm.nrm[tid] = rsqrtf((float)max(sm.cnt[tid], 1));
    if (tid < 64) {
        int v1 = (tid < NODES) ? sm.cnt[tid] : 0;
        int l2 = tid + 64;
        int v2 = (l2 < NODES) ? sm.cnt[l2] : 0;
        int s1 = v1;
#pragma unroll
        for (int d = 1; d < 64; d <<= 1) {
            int t2 = __shfl_up(s1, d, 64);
            if (tid >= d) s1 += t2;
        }
        int tot1 = __shfl(s1, 63, 64);
        int s2 = v2;
#pragma unroll
        for (int d = 1; d < 64; d <<= 1) {
            int t2 = __shfl_up(s2, d, 64);
            if (tid >= d) s2 += t2;
        }
        s2 += tot1;
        if (tid == 0) sm.row_start[0] = 0;
        sm.row_start[tid + 1] = s1;
        if (l2 < NODES) sm.row_start[l2 + 1] = s2;
    }
    __syncthreads();
    if (tid < NODES) sm.cnt[tid] = 0;   // reuse as CSR fill cursor
    __syncthreads();
    if (ethr) {
        int pos = atomicAdd(&sm.cnt[ed], 1);
        int slot = sm.row_start[ed] + pos;
        sm.csr_src[slot] = es;
        sm.csr_val[slot] = sm.nrm[es];
    }
    __syncthreads();

    // ---- 5 TAGConv layers ----
    tag_layer<74, 70>(sm, W0, b0, tid);
    tag_layer<70, 65>(sm, W1, b1, tid);
    tag_layer<65, 60>(sm, W2, b2, tid);
    tag_layer<60, 55>(sm, W3, b3, tid);
    tag_layer<55, 37>(sm, W4, b4, tid);
    // bufA: final h, 100 x 37, stride 76

    // ---- gate + softmax + pool ----
    if (tid < NODES) {
        float s = gate_b[0];
#pragma unroll
        for (int k = 0; k < 37; ++k)
            s = fmaf(sm.bufA[tid * STRIDE + k], gate_w[k], s);
        sm.gate[tid] = s;
    }
    __syncthreads();
    if (tid < 64) {
        float v1 = (tid < NODES) ? sm.gate[tid] : -INFINITY;
        float v2 = (tid + 64 < NODES) ? sm.gate[tid + 64] : -INFINITY;
        float m = fmaxf(v1, v2);
#pragma unroll
        for (int d = 32; d; d >>= 1) m = fmaxf(m, __shfl_xor(m, d, 64));
        float e1 = (tid < NODES) ? __expf(v1 - m) : 0.f;
        float e2 = (tid + 64 < NODES) ? __expf(v2 - m) : 0.f;
        float z = e1 + e2;
#pragma unroll
        for (int d = 32; d; d >>= 1) z += __shfl_xor(z, d, 64);
        float inv = 1.f / z;
        if (tid < NODES) sm.gate[tid] = e1 * inv;
        if (tid + 64 < NODES) sm.gate[tid + 64] = e2 * inv;
    }
    __syncthreads();
    if (tid < 37) {
        float p = 0.f;
        for (int n = 0; n < NODES; ++n)
            p = fmaf(sm.gate[n], sm.bufA[n * STRIDE + tid], p);
        out[g * 37 + tid] = p;
    }
}

extern "C" void kernel_launch(void* const* d_in, const int* in_sizes, int n_in,
                              void* d_out, int out_size, void* d_ws, size_t ws_size,
                              hipStream_t stream) {
    const float* x   = (const float*)d_in[0];
    const int*   src = (const int*)  d_in[1];
    const int*   dst = (const int*)  d_in[2];
    // d_in[3] = graph_ids (implicit: node / 100) -- unused
    const float* W0 = (const float*)d_in[4];  const float* b0 = (const float*)d_in[5];
    const float* W1 = (const float*)d_in[6];  const float* b1 = (const float*)d_in[7];
    const float* W2 = (const float*)d_in[8];  const float* b2 = (const float*)d_in[9];
    const float* W3 = (const float*)d_in[10]; const float* b3 = (const float*)d_in[11];
    const float* W4 = (const float*)d_in[12]; const float* b4 = (const float*)d_in[13];
    const float* gw = (const float*)d_in[14]; const float* gb = (const float*)d_in[15];
    float* out = (float*)d_out;

    drug_graph_conv_kernel<<<5000, NTHR, 0, stream>>>(
        x, src, dst, W0, b0, W1, b1, W2, b2, W3, b3, W4, b4, gw, gb, out);
}

// Round 6
// 1332.322 us; speedup vs baseline: 9.3103x; 9.3103x over previous
//
#include <hip/hip_runtime.h>
#include <math.h>

// DrugGraphConv: 5000 graphs x 100 nodes x 400 edges, 5 TAGConv(K=2) layers
// DIMS = [74,70,65,60,55,37], gated softmax pooling per graph.
//
// R4 (3.49ms): lane=node + SGPR W -> no spills, but s_load(W) and ds_read(h)
// share lgkmcnt (out-of-order SMEM => full drains) -> VALUBusy 28%.
// R5 (12.4ms): LDS 66,048B > 64KB halved occupancy (co-residency pool is
// 128KB: 2x66,048 > 131,072), full unroll pushed VGPR to 128.
//
// R6: W repacked by a pre-kernel into a static device array, padded to
// (D_INP x CW4) per wave-slice -> gblock W loads are per-lane
// global_load_dwordx4 on vmcnt (decoupled from LDS lgkmcnt), no tail logic.
// LDS trimmed to 64,404B (ushort csr_src, cnt/gate union) -> 2 blocks/CU.
// Chunk loop unroll 1: 1 ds_read_b128 + <=20 dwordx4 + <=80 FMA per iter.

constexpr int NODES  = 100;
constexpr int EDGES  = 400;
constexpr int STRIDE = 76;     // mult of 4: b128 rows 2-way-bank-free
constexpr int NTHR   = 512;

// packed W: per layer, per (b,cgrp): D_INP rows x CW4 cols, zero-padded.
// sizes: 12*76*20 + 12*72*20 + 12*68*16 + 12*60*16 + 12*56*12 = 68,160 floats
__device__ __align__(16) float g_packW[68160];

struct __align__(16) Smem {
    float bufA[NODES * STRIDE];        // 30,400 B
    float bufB[NODES * STRIDE];        // 30,400 B
    float csr_val[EDGES];              //  1,600 B (nrm[src] per CSR slot)
    unsigned short csr_src[EDGES];     //    800 B (src node ids < 100)
    int   row_start[NODES + 1];        //    404 B
    int   cntg[NODES];                 //    400 B (cnt during setup, gate after)
    float nrm[NODES];                  //    400 B  => 64,404 B (2 blocks/CU)
};

// ---------------- repack kernel ----------------
template<int D_IN, int D_OUT, int CW4, int D_INP, int WOFF>
__device__ __forceinline__ void repack_layer(const float* __restrict__ W, int idx) {
    constexpr int SZ = 12 * D_INP * CW4;
    if (idx >= SZ) return;
    int j = idx % CW4;
    int r = idx / CW4;
    int k = r % D_INP;
    int q = r / D_INP;          // b*4 + cgrp
    int cgrp = q & 3;
    int b = q >> 2;
    int col = cgrp * CW4 + j;
    float v = 0.f;
    if (col < D_OUT && k < D_IN) v = W[(b * D_IN + k) * D_OUT + col];
    g_packW[WOFF + idx] = v;
}

__global__ void repack_kernel(const float* __restrict__ W0, const float* __restrict__ W1,
                              const float* __restrict__ W2, const float* __restrict__ W3,
                              const float* __restrict__ W4) {
    int idx = blockIdx.x * 256 + threadIdx.x;
    switch (blockIdx.y) {
    case 0: repack_layer<74, 70, 20, 76,     0>(W0, idx); break;
    case 1: repack_layer<70, 65, 20, 72, 18240>(W1, idx); break;
    case 2: repack_layer<65, 60, 16, 68, 35520>(W2, idx); break;
    case 3: repack_layer<60, 55, 16, 60, 48576>(W3, idx); break;
    case 4: repack_layer<55, 37, 12, 56, 60096>(W4, idx); break;
    }
}

// ---------------- propagation (CSR gather) ----------------
// out[n][:] = nrm[n] * sum_{e: dst==n} csr_val[e] * in[src_e][:]
template<int D_IN>
__device__ __forceinline__ void propagate(const float* __restrict__ in,
                                          float* __restrict__ outb,
                                          const unsigned short* __restrict__ csr_src,
                                          const float* __restrict__ csr_val,
                                          const int* __restrict__ row_start,
                                          const float* __restrict__ nrm,
                                          int tid)
{
    constexpr int CH = (D_IN + 3) / 4;            // float4 chunks (pad finite)
    constexpr int R4 = STRIDE / 4;                // 19 float4 per row
    const float4* __restrict__ in4 = (const float4*)in;
    float4* __restrict__ out4 = (float4*)outb;

    for (int t = tid; t < NODES * CH; t += NTHR) {
        int n = t / CH;                           // compile-time divisor
        int c = t - n * CH;
        int beg = row_start[n], end = row_start[n + 1];
        float ax = 0.f, ay = 0.f, az = 0.f, aw = 0.f;
        int e = beg;
        for (; e + 3 < end; e += 4) {
            int   s0 = csr_src[e],     s1 = csr_src[e + 1];
            int   s2 = csr_src[e + 2], s3 = csr_src[e + 3];
            float c0 = csr_val[e],     c1 = csr_val[e + 1];
            float c2 = csr_val[e + 2], c3 = csr_val[e + 3];
            float4 v0 = in4[s0 * R4 + c];
            float4 v1 = in4[s1 * R4 + c];
            float4 v2 = in4[s2 * R4 + c];
            float4 v3 = in4[s3 * R4 + c];
            ax = fmaf(c0, v0.x, ax); ay = fmaf(c0, v0.y, ay);
            az = fmaf(c0, v0.z, az); aw = fmaf(c0, v0.w, aw);
            ax = fmaf(c1, v1.x, ax); ay = fmaf(c1, v1.y, ay);
            az = fmaf(c1, v1.z, az); aw = fmaf(c1, v1.w, aw);
            ax = fmaf(c2, v2.x, ax); ay = fmaf(c2, v2.y, ay);
            az = fmaf(c2, v2.z, az); aw = fmaf(c2, v2.w, aw);
            ax = fmaf(c3, v3.x, ax); ay = fmaf(c3, v3.y, ay);
            az = fmaf(c3, v3.z, az); aw = fmaf(c3, v3.w, aw);
        }
        for (; e < end; ++e) {
            int s = csr_src[e];
            float sc = csr_val[e];
            float4 v = in4[s * R4 + c];
            ax = fmaf(sc, v.x, ax); ay = fmaf(sc, v.y, ay);
            az = fmaf(sc, v.z, az); aw = fmaf(sc, v.w, aw);
        }
        float sn = nrm[n];
        float4 o = { ax * sn, ay * sn, az * sn, aw * sn };
        out4[n * R4 + c] = o;
    }
}

// ---------------- one TAGConv layer ----------------
template<int D_IN, int D_OUT, int CW4, int D_INP, int WOFF>
__device__ __forceinline__ void tag_layer(Smem& sm,
                                          const float* __restrict__ Bv,
                                          int tid)
{
    constexpr int Q   = CW4 / 4;                  // float4 W loads per k row
    constexpr int CHP = D_INP / 4;                // h chunks

    const int wave    = __builtin_amdgcn_readfirstlane(tid >> 6); // uniform
    const int lane    = tid & 63;
    const int cgrp    = wave >> 1;                // 0..3 uniform
    const int nhalf   = wave & 1;                 // 0..1 uniform
    const int node    = nhalf * 64 + lane;
    const int nclamp  = node > NODES - 1 ? NODES - 1 : node;
    const int colbase = cgrp * CW4;               // uniform

    float acc[CW4];
#pragma unroll
    for (int j = 0; j < CW4; ++j) acc[j] = 0.f;

    auto gblock = [&](const float* __restrict__ buf, int b) {
        const float4* __restrict__ wb =
            (const float4*)&g_packW[WOFF + (b * 4 + cgrp) * D_INP * CW4];
        const float4* __restrict__ hrow4 = (const float4*)(buf + nclamp * STRIDE);
#pragma unroll 1
        for (int cc = 0; cc < CHP; ++cc) {
            const float4 h4 = hrow4[cc];          // ds_read_b128 (lgkmcnt)
            const float4* __restrict__ wk = wb + cc * 4 * Q;  // vmcnt loads
            const float hv0 = h4.x, hv1 = h4.y, hv2 = h4.z, hv3 = h4.w;
#pragma unroll
            for (int q = 0; q < Q; ++q) {
                float4 w0 = wk[0 * Q + q];
                float4 w1 = wk[1 * Q + q];
                float4 w2 = wk[2 * Q + q];
                float4 w3 = wk[3 * Q + q];
                acc[4*q+0] = fmaf(hv3, w3.x, fmaf(hv2, w2.x, fmaf(hv1, w1.x, fmaf(hv0, w0.x, acc[4*q+0]))));
                acc[4*q+1] = fmaf(hv3, w3.y, fmaf(hv2, w2.y, fmaf(hv1, w1.y, fmaf(hv0, w0.y, acc[4*q+1]))));
                acc[4*q+2] = fmaf(hv3, w3.z, fmaf(hv2, w2.z, fmaf(hv1, w1.z, fmaf(hv0, w0.z, acc[4*q+2]))));
                acc[4*q+3] = fmaf(hv3, w3.w, fmaf(hv2, w2.w, fmaf(hv1, w1.w, fmaf(hv0, w0.w, acc[4*q+3]))));
            }
        }
    };

    // feats block 0: h (bufA); then hop1 bufA->bufB (bufB dead, no race)
    gblock(sm.bufA, 0);
    propagate<D_IN>(sm.bufA, sm.bufB, sm.csr_src, sm.csr_val,
                    sm.row_start, sm.nrm, tid);
    __syncthreads();
    // feats block 1: hop1 (bufB); then hop2 bufB->bufA (bufA reads all done)
    gblock(sm.bufB, 1);
    propagate<D_IN>(sm.bufB, sm.bufA, sm.csr_src, sm.csr_val,
                    sm.row_start, sm.nrm, tid);
    __syncthreads();
    // feats block 2: hop2 (bufA)
    gblock(sm.bufA, 2);
    __syncthreads();    // all reads of bufA complete before h' overwrite

    if (node < NODES) {
#pragma unroll
        for (int j = 0; j < CW4; ++j) {
            int c = colbase + j;          // uniform per j
            if (c < D_OUT)
                sm.bufA[node * STRIDE + c] = fmaxf(acc[j] + Bv[c], 0.f);
        }
    }
    __syncthreads();
}

__global__ __launch_bounds__(NTHR, 2)
void drug_graph_conv_kernel(
    const float* __restrict__ x,
    const int*   __restrict__ src,
    const int*   __restrict__ dst,
    const float* __restrict__ b0, const float* __restrict__ b1,
    const float* __restrict__ b2, const float* __restrict__ b3,
    const float* __restrict__ b4,
    const float* __restrict__ gate_w, const float* __restrict__ gate_b,
    float* __restrict__ out)
{
    __shared__ Smem sm;
    const int g     = blockIdx.x;
    const int tid   = threadIdx.x;
    const int nbase = g * NODES;

    // ---- stage x (100 x 74) into bufA at stride 76; zero pad cols 74,75 ----
    for (int t = tid; t < NODES * 74; t += NTHR) {
        int n = t / 74;
        int d = t - n * 74;
        sm.bufA[n * STRIDE + d] = x[nbase * 74 + t];
    }
    for (int t = tid; t < NODES * 2; t += NTHR) {
        int n = t >> 1;
        sm.bufA[n * STRIDE + 74 + (t & 1)] = 0.f;
    }

    // ---- degree count ----
    if (tid < NODES) sm.cntg[tid] = 0;
    __syncthreads();
    int es = 0, ed = 0;
    const bool ethr = tid < EDGES;
    if (ethr) {
        es = src[g * EDGES + tid] - nbase;
        ed = dst[g * EDGES + tid] - nbase;
        atomicAdd(&sm.cntg[ed], 1);
    }
    __syncthreads();

    // ---- norm + CSR row offsets (wave-0 shuffle scan over 100 degrees) ----
    if (tid < NODES) sm.nrm[tid] = rsqrtf((float)max(sm.cntg[tid], 1));
    if (tid < 64) {
        int v1 = (tid < NODES) ? sm.cntg[tid] : 0;
        int l2 = tid + 64;
        int v2 = (l2 < NODES) ? sm.cntg[l2] : 0;
        int s1 = v1;
#pragma unroll
        for (int d = 1; d < 64; d <<= 1) {
            int t2 = __shfl_up(s1, d, 64);
            if (tid >= d) s1 += t2;
        }
        int tot1 = __shfl(s1, 63, 64);
        int s2 = v2;
#pragma unroll
        for (int d = 1; d < 64; d <<= 1) {
            int t2 = __shfl_up(s2, d, 64);
            if (tid >= d) s2 += t2;
        }
        s2 += tot1;
        if (tid == 0) sm.row_start[0] = 0;
        sm.row_start[tid + 1] = s1;
        if (l2 < NODES) sm.row_start[l2 + 1] = s2;
    }
    __syncthreads();
    if (tid < NODES) sm.cntg[tid] = 0;   // reuse as CSR fill cursor
    __syncthreads();
    if (ethr) {
        int pos = atomicAdd(&sm.cntg[ed], 1);
        int slot = sm.row_start[ed] + pos;
        sm.csr_src[slot] = (unsigned short)es;
        sm.csr_val[slot] = sm.nrm[es];
    }
    __syncthreads();

    // ---- 5 TAGConv layers ----
    tag_layer<74, 70, 20, 76,     0>(sm, b0, tid);
    tag_layer<70, 65, 20, 72, 18240>(sm, b1, tid);
    tag_layer<65, 60, 16, 68, 35520>(sm, b2, tid);
    tag_layer<60, 55, 16, 60, 48576>(sm, b3, tid);
    tag_layer<55, 37, 12, 56, 60096>(sm, b4, tid);
    // bufA: final h, 100 x 37, stride 76

    // ---- gate + softmax + pool (gate stored in cntg as float) ----
    float* gate = (float*)sm.cntg;
    if (tid < NODES) {
        float s = gate_b[0];
#pragma unroll
        for (int k = 0; k < 37; ++k)
            s = fmaf(sm.bufA[tid * STRIDE + k], gate_w[k], s);
        gate[tid] = s;
    }
    __syncthreads();
    if (tid < 64) {
        float v1 = (tid < NODES) ? gate[tid] : -INFINITY;
        float v2 = (tid + 64 < NODES) ? gate[tid + 64] : -INFINITY;
        float m = fmaxf(v1, v2);
#pragma unroll
        for (int d = 32; d; d >>= 1) m = fmaxf(m, __shfl_xor(m, d, 64));
        float e1 = (tid < NODES) ? __expf(v1 - m) : 0.f;
        float e2 = (tid + 64 < NODES) ? __expf(v2 - m) : 0.f;
        float z = e1 + e2;
#pragma unroll
        for (int d = 32; d; d >>= 1) z += __shfl_xor(z, d, 64);
        float inv = 1.f / z;
        if (tid < NODES) gate[tid] = e1 * inv;
        if (tid + 64 < NODES) gate[tid + 64] = e2 * inv;
    }
    __syncthreads();
    if (tid < 37) {
        float p = 0.f;
        for (int n = 0; n < NODES; ++n)
            p = fmaf(gate[n], sm.bufA[n * STRIDE + tid], p);
        out[g * 37 + tid] = p;
    }
}

extern "C" void kernel_launch(void* const* d_in, const int* in_sizes, int n_in,
                              void* d_out, int out_size, void* d_ws, size_t ws_size,
                              hipStream_t stream) {
    const float* x   = (const float*)d_in[0];
    const int*   src = (const int*)  d_in[1];
    const int*   dst = (const int*)  d_in[2];
    // d_in[3] = graph_ids (implicit: node / 100) -- unused
    const float* W0 = (const float*)d_in[4];  const float* b0 = (const float*)d_in[5];
    const float* W1 = (const float*)d_in[6];  const float* b1 = (const float*)d_in[7];
    const float* W2 = (const float*)d_in[8];  const float* b2 = (const float*)d_in[9];
    const float* W3 = (const float*)d_in[10]; const float* b3 = (const float*)d_in[11];
    const float* W4 = (const float*)d_in[12]; const float* b4 = (const float*)d_in[13];
    const float* gw = (const float*)d_in[14]; const float* gb = (const float*)d_in[15];
    float* out = (float*)d_out;

    // repack W (max layer 18,240 elems -> 72 blocks of 256, y = layer)
    dim3 rg(72, 5, 1);
    repack_kernel<<<rg, 256, 0, stream>>>(W0, W1, W2, W3, W4);

    drug_graph_conv_kernel<<<5000, NTHR, 0, stream>>>(
        x, src, dst, b0, b1, b2, b3, b4, gw, gb, out);
}